// Round 3
// baseline (1359.982 us; speedup 1.0000x reference)
//
#include <hip/hip_runtime.h>

typedef unsigned long long u64;
typedef unsigned int u32;

#define W1H 1023   // after conv1+pool
#define W2H 1021   // after conv2
#define W3H 1019   // after conv3
#define NPIX (W3H * W3H)          // 1,038,361 < 2^20
#define IDXMASK 0xFFFFFull

// ---------------- conv1 (3->10, 3x3) + bias + prelu + maxpool2, f64 ----------------
__global__ __launch_bounds__(256) void k_conv1(
    const float* __restrict__ x, const float* __restrict__ w1,
    const float* __restrict__ b1, const float* __restrict__ p1,
    double* __restrict__ P)
{
    __shared__ double sw[270];
    __shared__ double sb[10], sp[10];
    int t = threadIdx.y * 64 + threadIdx.x;
    for (int i = t; i < 270; i += 256) sw[i] = (double)w1[i];   // FIX: was if(t<270) with 256 threads
    if (t < 10) { sb[t] = (double)b1[t]; sp[t] = (double)p1[t]; }
    __syncthreads();
    int px = blockIdx.x * 64 + threadIdx.x;
    int py = blockIdx.y * 4 + threadIdx.y;
    if (px >= W1H || py >= W1H) return;
    int ix = px * 2, iy = py * 2;
    double acc[10][4];
    #pragma unroll
    for (int ch = 0; ch < 10; ++ch) {
        acc[ch][0] = 0.0; acc[ch][1] = 0.0; acc[ch][2] = 0.0; acc[ch][3] = 0.0;
    }
    for (int c = 0; c < 3; ++c) {
        double in[4][4];
        #pragma unroll
        for (int u = 0; u < 4; ++u) {
            const float* row = x + ((size_t)c * 2048 + (iy + u)) * 2048 + ix;
            in[u][0] = (double)row[0]; in[u][1] = (double)row[1];
            in[u][2] = (double)row[2]; in[u][3] = (double)row[3];
        }
        #pragma unroll
        for (int ch = 0; ch < 10; ++ch) {
            const double* wp = sw + (ch * 3 + c) * 9;
            #pragma unroll
            for (int u = 0; u < 3; ++u)
                #pragma unroll
                for (int v = 0; v < 3; ++v) {
                    double w = wp[u * 3 + v];
                    acc[ch][0] = fma(in[u][v],         w, acc[ch][0]);
                    acc[ch][1] = fma(in[u][v + 1],     w, acc[ch][1]);
                    acc[ch][2] = fma(in[u + 1][v],     w, acc[ch][2]);
                    acc[ch][3] = fma(in[u + 1][v + 1], w, acc[ch][3]);
                }
        }
    }
    #pragma unroll
    for (int ch = 0; ch < 10; ++ch) {
        // prelu monotone (p>=0), +bias monotone => exact vs conv->bias->prelu->maxpool
        double m = fmax(fmax(acc[ch][0], acc[ch][1]), fmax(acc[ch][2], acc[ch][3])) + sb[ch];
        double r = m >= 0.0 ? m : sp[ch] * m;
        P[((size_t)ch * W1H + py) * W1H + px] = r;
    }
}

// ---------------- conv2 (10->16, 3x3) + bias + prelu, f64 ----------------
__global__ __launch_bounds__(256) void k_conv2(
    const double* __restrict__ P, const float* __restrict__ w2,
    const float* __restrict__ b2, const float* __restrict__ p2,
    double* __restrict__ H2)
{
    __shared__ double sw[1440];   // [c][o][9]
    __shared__ double sb[16], sp[16];
    int t = threadIdx.y * 64 + threadIdx.x;
    for (int i = t; i < 1440; i += 256) {
        int o = i / 90, r = i % 90, c = r / 9, k = r % 9;
        sw[(c * 16 + o) * 9 + k] = (double)w2[i];
    }
    if (t < 16) { sb[t] = (double)b2[t]; sp[t] = (double)p2[t]; }
    __syncthreads();
    int px = blockIdx.x * 64 + threadIdx.x;
    int py = blockIdx.y * 4 + threadIdx.y;
    if (px >= W2H || py >= W2H) return;
    double acc[16];
    #pragma unroll
    for (int o = 0; o < 16; ++o) acc[o] = 0.0;
    for (int c = 0; c < 10; ++c) {
        double in[9];
        #pragma unroll
        for (int u = 0; u < 3; ++u) {
            const double* row = P + ((size_t)c * W1H + py + u) * W1H + px;
            in[u * 3] = row[0]; in[u * 3 + 1] = row[1]; in[u * 3 + 2] = row[2];
        }
        const double* wc = sw + c * 144;
        #pragma unroll
        for (int o = 0; o < 16; ++o) {
            const double* wp = wc + o * 9;
            double s = acc[o];
            #pragma unroll
            for (int k = 0; k < 9; ++k) s = fma(in[k], wp[k], s);
            acc[o] = s;
        }
    }
    #pragma unroll
    for (int o = 0; o < 16; ++o) {
        double v = acc[o] + sb[o];
        v = v >= 0.0 ? v : sp[o] * v;
        H2[((size_t)o * W2H + py) * W2H + px] = v;
    }
}

// ------- conv3 (16->32) + prelu + cls head + softmax + candidate push, f64 -------
__global__ __launch_bounds__(256) void k_conv3(
    const double* __restrict__ H2, const float* __restrict__ w3,
    const float* __restrict__ b3, const float* __restrict__ p3,
    const float* __restrict__ wa, const float* __restrict__ ba,
    u64* __restrict__ cand, int* __restrict__ counter)
{
    __shared__ double sw[4608];   // [c][o][9]
    __shared__ double sb[32], sp[32], swa[64], sba[2];
    int t = threadIdx.y * 64 + threadIdx.x;
    for (int i = t; i < 4608; i += 256) {
        int o = i / 144, rem = i % 144, c = rem / 9, k = rem % 9;
        sw[(c * 32 + o) * 9 + k] = (double)w3[i];
    }
    if (t < 32) { sb[t] = (double)b3[t]; sp[t] = (double)p3[t]; }
    if (t < 64) swa[t] = (double)wa[t];
    if (t < 2)  sba[t] = (double)ba[t];
    __syncthreads();
    int px = blockIdx.x * 64 + threadIdx.x;
    int py = blockIdx.y * 4 + threadIdx.y;
    if (px >= W3H || py >= W3H) return;
    double acc[32];
    #pragma unroll
    for (int o = 0; o < 32; ++o) acc[o] = 0.0;
    for (int c = 0; c < 16; ++c) {
        double in[9];
        #pragma unroll
        for (int u = 0; u < 3; ++u) {
            const double* row = H2 + ((size_t)c * W2H + py + u) * W2H + px;
            in[u * 3] = row[0]; in[u * 3 + 1] = row[1]; in[u * 3 + 2] = row[2];
        }
        const double* wc = sw + c * 288;
        #pragma unroll
        for (int o = 0; o < 32; ++o) {
            const double* wp = wc + o * 9;
            double s = acc[o];
            #pragma unroll
            for (int k = 0; k < 9; ++k) s = fma(in[k], wp[k], s);
            acc[o] = s;
        }
    }
    double c0 = sba[0], c1 = sba[1];
    #pragma unroll
    for (int o = 0; o < 32; ++o) {
        double v = acc[o] + sb[o];
        v = v >= 0.0 ? v : sp[o] * v;
        c0 = fma(swa[o], v, c0);
        c1 = fma(swa[32 + o], v, c1);
    }
    // prob >= 0.6  <=>  c1-c0 >= ln(1.5)=0.4054651 in exact math; 0.405 = safe prefilter
    if (c1 - c0 > 0.405) {
        double mx = fmax(c0, c1);
        double e0 = exp(c0 - mx), e1 = exp(c1 - mx);
        double prob = e1 / (e0 + e1);
        if (prob >= 0.6) {
            int slot = atomicAdd(counter, 1);
            if (slot < NPIX) {
                u32 idx = (u32)(py * W3H + px);
                u64 bits = (u64)__double_as_longlong(prob);   // prob in (0.5,1]: bits monotone
                cand[slot] = (bits & ~IDXMASK) | (u64)((~idx) & IDXMASK);
            }
        }
    }
}

__global__ void k_zero(int* c) { if (threadIdx.x == 0) *c = 0; }

// ------- pass B: each block sorts 4 chunks of 512, keeps local top-512 (desc) -------
__global__ __launch_bounds__(512) void k_sortchunks(
    const u64* __restrict__ cand, const int* __restrict__ counter,
    u64* __restrict__ sorted)
{
    __shared__ u64 stop_[512];
    __shared__ u64 schunk[512];
    int tid = threadIdx.x;
    int n = *counter; if (n > NPIX) n = NPIX;
    long base0 = (long)blockIdx.x * 2048;
    if (base0 >= n) return;                       // chunk never read by pass C
    stop_[tid] = 0ull;
    for (int s = 0; s < 4; ++s) {
        long base = base0 + (long)s * 512;
        if (base >= n) break;                     // uniform per block
        schunk[tid] = (base + tid < n) ? cand[base + tid] : 0ull;
        for (int k = 2; k <= 512; k <<= 1)
            for (int j = k >> 1; j > 0; j >>= 1) {
                __syncthreads();
                int ixj = tid ^ j;
                if (ixj > tid) {
                    u64 a = schunk[tid], b = schunk[ixj];
                    bool desc = ((tid & k) == 0);
                    if (desc ? (a < b) : (a > b)) { schunk[tid] = b; schunk[ixj] = a; }
                }
            }
        __syncthreads();
        // top-512 of union: elementwise max vs reversed chunk -> bitonic, then merge desc
        u64 m = stop_[tid], v = schunk[511 - tid];
        stop_[tid] = m > v ? m : v;
        for (int j = 256; j > 0; j >>= 1) {
            __syncthreads();
            int ixj = tid ^ j;
            if (ixj > tid) {
                u64 a = stop_[tid], b = stop_[ixj];
                if (a < b) { stop_[tid] = b; stop_[ixj] = a; }
            }
        }
        __syncthreads();
    }
    sorted[(size_t)blockIdx.x * 512 + tid] = stop_[tid];
}

// ------- pass C: merge <=508 sorted chunks -> global top-512; reg head; boxes; 2x NMS -------
__global__ __launch_bounds__(512) void k_final(
    const u64* __restrict__ sorted, const int* __restrict__ counter,
    const double* __restrict__ H2,
    const float* __restrict__ w3, const float* __restrict__ b3, const float* __restrict__ p3,
    const float* __restrict__ wb, const float* __restrict__ bb,
    float* __restrict__ out)
{
    __shared__ u64 stop_[512];
    // phase1: w3 weights (36864 B); phase2 (after recompute): box arrays (5*4096 B)
    __shared__ __align__(16) char smem[36864];
    __shared__ double sb3[32], sp3[32], swb[128], sbb[4];
    __shared__ double sscore_[512];
    __shared__ int keep[512];

    double* sw = (double*)smem;                  // [o*16+c]*9+k (raw w3 layout)
    int tid = threadIdx.x;
    for (int i = tid; i < 4608; i += 512) sw[i] = (double)w3[i];
    if (tid < 32) { sb3[tid] = (double)b3[tid]; sp3[tid] = (double)p3[tid]; }
    if (tid < 128) swb[tid] = (double)wb[tid];
    if (tid < 4)   sbb[tid] = (double)bb[tid];
    stop_[tid] = 0ull;
    __syncthreads();

    int n = *counter; if (n > NPIX) n = NPIX;
    int nb = (n + 2047) / 2048;

    for (int cb = 0; cb < nb; ++cb) {
        u64 v = sorted[(size_t)cb * 512 + (511 - tid)];
        u64 m = stop_[tid];
        stop_[tid] = m > v ? m : v;
        for (int j = 256; j > 0; j >>= 1) {
            __syncthreads();
            int ixj = tid ^ j;
            if (ixj > tid) {
                u64 a = stop_[tid], b = stop_[ixj];
                if (a < b) { stop_[tid] = b; stop_[ixj] = a; }
            }
        }
        __syncthreads();
    }

    u64 key = stop_[tid];
    bool valid = key != 0ull;
    double score = valid ? __longlong_as_double((long long)(key & ~IDXMASK)) : 0.0;
    u32 idx = valid ? (u32)(IDXMASK - (key & IDXMASK)) : 0u;
    int yy = (int)(idx / W3H), xx = (int)(idx % W3H);

    double r0 = 0.0, r1 = 0.0, r2 = 0.0, r3 = 0.0;
    if (valid) {
        double acc[32];
        #pragma unroll
        for (int o = 0; o < 32; ++o) acc[o] = 0.0;
        for (int c = 0; c < 16; ++c) {
            double in[9];
            #pragma unroll
            for (int u = 0; u < 3; ++u) {
                const double* row = H2 + ((size_t)c * W2H + yy + u) * W2H + xx;
                in[u * 3] = row[0]; in[u * 3 + 1] = row[1]; in[u * 3 + 2] = row[2];
            }
            #pragma unroll
            for (int o = 0; o < 32; ++o) {
                const double* wp = sw + (o * 16 + c) * 9;
                double s = acc[o];
                #pragma unroll
                for (int k2 = 0; k2 < 9; ++k2) s = fma(in[k2], wp[k2], s);
                acc[o] = s;
            }
        }
        r0 = sbb[0]; r1 = sbb[1]; r2 = sbb[2]; r3 = sbb[3];
        #pragma unroll
        for (int o = 0; o < 32; ++o) {
            double v = acc[o] + sb3[o];
            v = v >= 0.0 ? v : sp3[o] * v;
            r0 = fma(swb[o], v, r0);
            r1 = fma(swb[32 + o], v, r1);
            r2 = fma(swb[64 + o], v, r2);
            r3 = fma(swb[96 + o], v, r3);
        }
    }
    __syncthreads();   // sw dead from here; alias smem as box arrays

    double* bx1 = (double*)smem;
    double* by1 = bx1 + 512;
    double* bx2 = bx1 + 1024;
    double* by2 = bx1 + 1536;
    double* sarea = bx1 + 2048;

    double fx = (double)xx, fy = (double)yy;
    double cx = (fx * 2.0 + 6.0) / 0.6;     // off_x = ((2048-12)%2)/2 + 6 = 6.0 exact
    double cy = (fy * 2.0 + 6.0) / 0.6;
    double ww = 12.0 / 0.6;
    double hw = ww / 2.0;
    double x1 = cx - hw + r0 * ww;
    double y1 = cy - hw + r1 * ww;
    double x2 = cx + hw + r2 * ww;
    double y2 = cy + hw + r3 * ww;
    bx1[tid] = x1; by1[tid] = y1; bx2[tid] = x2; by2[tid] = y2;
    sarea[tid] = (x2 - x1) * (y2 - y1);
    sscore_[tid] = score;
    keep[tid] = valid ? 1 : 0;

    // two greedy NMS passes: thr=0.5 then 0.7 (f64, exact vs np)
    for (int pass = 0; pass < 2; ++pass) {
        double thr = (pass == 0) ? 0.5 : 0.7;
        for (int i = 0; i < 511; ++i) {
            __syncthreads();
            if (keep[i] == 0) continue;   // uniform read
            double xi1 = bx1[i], yi1 = by1[i], xi2 = bx2[i], yi2 = by2[i], ai = sarea[i];
            if (tid > i && keep[tid]) {
                double ix1 = fmax(xi1, bx1[tid]);
                double iy1 = fmax(yi1, by1[tid]);
                double ix2 = fmin(xi2, bx2[tid]);
                double iy2 = fmin(yi2, by2[tid]);
                double inter = fmax(ix2 - ix1, 0.0) * fmax(iy2 - iy1, 0.0);
                double iou = inter / (ai + sarea[tid] - inter + 1e-9);
                if (iou > thr) keep[tid] = 0;
            }
        }
        __syncthreads();
    }

    double kf = keep[tid] ? 1.0 : 0.0;
    out[tid * 5 + 0] = (float)(x1 * kf);
    out[tid * 5 + 1] = (float)(y1 * kf);
    out[tid * 5 + 2] = (float)(x2 * kf);
    out[tid * 5 + 3] = (float)(y2 * kf);
    out[tid * 5 + 4] = (float)(sscore_[tid] * kf);
}

extern "C" void kernel_launch(void* const* d_in, const int* in_sizes, int n_in,
                              void* d_out, int out_size, void* d_ws, size_t ws_size,
                              hipStream_t stream)
{
    const float* x  = (const float*)d_in[0];
    const float* w1 = (const float*)d_in[1];
    const float* b1 = (const float*)d_in[2];
    const float* p1 = (const float*)d_in[3];
    const float* w2 = (const float*)d_in[4];
    const float* b2 = (const float*)d_in[5];
    const float* p2 = (const float*)d_in[6];
    const float* w3 = (const float*)d_in[7];
    const float* b3 = (const float*)d_in[8];
    const float* p3 = (const float*)d_in[9];
    const float* wa = (const float*)d_in[10];
    const float* ba = (const float*)d_in[11];
    const float* wb = (const float*)d_in[12];
    const float* bb = (const float*)d_in[13];
    float* out = (float*)d_out;

    char* ws = (char*)d_ws;
    double* P      = (double*)(ws);                    // 10*1023^2*8 = 83,722,320 B
    double* H2     = (double*)(ws + 83722496);         // 16*1021^2*8 = 133,432,448 B
    int*    counter= (int*)   (ws + 217154944);
    u64*    cand   = (u64*)   (ws + 217155200);        // NPIX*8 = 8,306,888 B
    u64*    sorted = (u64*)   (ws + 225462272);        // 508*512*8 = 2,080,768 B

    k_zero<<<1, 64, 0, stream>>>(counter);
    k_conv1<<<dim3(16, 256), dim3(64, 4), 0, stream>>>(x, w1, b1, p1, P);
    k_conv2<<<dim3(16, 256), dim3(64, 4), 0, stream>>>(P, w2, b2, p2, H2);
    k_conv3<<<dim3(16, 255), dim3(64, 4), 0, stream>>>(H2, w3, b3, p3, wa, ba, cand, counter);
    k_sortchunks<<<508, 512, 0, stream>>>(cand, counter, sorted);
    k_final<<<1, 512, 0, stream>>>(sorted, counter, H2, w3, b3, p3, wb, bb, out);
}